// Round 15
// baseline (89.574 us; speedup 1.0000x reference)
//
#include <hip/hip_runtime.h>
#include <hip/hip_bf16.h>

// MoE fused kernel for MI355X (gfx950) — R15: R14 + pairwise spin-sync.
// out[t,o] = sum_e w[t,e] * (relu(x[t]@W1[e]^T) @ W2[e]^T),
// w = softmax_e(mask( relu(x@sg1^T)@(gate_w@sg_w2)^T + x@gate_w^T ))
//
// 512 blocks x 256 thr (4 waves = lw{0,1} token-groups x hf{0,1} expert
// halves), 2 blocks/CU, 2 waves/SIMD. Each wave: 64 tokens x 4 experts.
// The hf0 pair (waves 0,1) and hf1 pair (waves 2,3) share NO data (disjoint
// ring regions/weight streams) — R14's block-wide s_barrier over-synced 2x.
// R15: pairwise LDS spin-sync (single-writer monotonic epoch counters:
// vmcnt(0) -> publish own epoch -> poll partner >= epoch). 4 independent
// streams/CU (2 blocks x 2 pairs) average out load-latency jitter.
// Expert math verified R5-R14: G1 swapped mfma(W1,X)->D[hid][token];
// W2 prep-packed (chunk-major, permuted k-order) so relu*w + bf16-pack of
// the G1 accumulator IS a legal G2 B-fragment; G2 swapped -> D[out][token].
// Halves combined via the R10/R14-verified 2-round LDS epilogue.

typedef float f32x4 __attribute__((ext_vector_type(4)));
typedef short bf16x8 __attribute__((ext_vector_type(8)));

static __device__ __forceinline__ short f2bs(float f) {
  union { __hip_bfloat16 b; short s; } u;
  u.b = __float2bfloat16(f);
  return u.s;
}

static __device__ __forceinline__ unsigned pk2(float lo, float hi) {
  union { __hip_bfloat162 b; unsigned u; } t;
  t.b = __float22bfloat162_rn(make_float2(lo, hi));
  return t.u;
}

// ws layout (shorts):
//  [0,262144)       W1p : (c*8 + i)*512 + lane*8 + j, c=e*8+ks, i=n*4+kx
//                         = W1[e][ks*32+n*16+l15][kx*32+lg*8+j]
//  [262144,524288)  W2p : (c*8 + oi)*512 + lane*8 + j   (chunk-major)
//                         = W2[e][oi*16+l15][ks*32 + perm(lg,j)]
//                           perm(lg,j) = j<4 ? lg*4+j : 16+lg*4+(j-4)
//  [524288,526336)  sg1p: k*512 + lane*8 + j = sg_w1[l15][k*32+lg*8+j]
//  [526336,528384)  gwp : k*512 + lane*8 + j = l15<8 ? gate_w[l15][...] : 0
//  [528384,528896)  gcp : lane*8 + j = (l15<8 && lg*8+j<16) ? gc[l15][lg*8+j] : 0
//                         gc = gate_w @ sg_w2  [8,16]

__global__ void prep_kernel(const float* __restrict__ sg_w1,
                            const float* __restrict__ sg_w2,
                            const float* __restrict__ gate_w,
                            const float* __restrict__ exp_w1,
                            const float* __restrict__ exp_w2,
                            short* __restrict__ ws_s) {
  int idx = blockIdx.x * 256 + threadIdx.x;
  if (idx < 262144) {
    int e = idx >> 15, rem = idx & 32767;
    int frag = rem >> 9, lane = (rem >> 3) & 63, j = rem & 7;
    int hid = (frag >> 2) * 16 + (lane & 15);
    int k   = (frag & 3) * 32 + (lane >> 4) * 8 + j;
    ws_s[idx] = f2bs(exp_w1[(e * 256 + hid) * 128 + k]);
  } else if (idx < 524288) {
    int i2 = idx - 262144;
    int e = i2 >> 15, rem = i2 & 32767;
    int frag = rem >> 9, lane = (rem >> 3) & 63, j = rem & 7;
    int lg = lane >> 4, l15 = lane & 15;
    int ks = frag >> 3;          // chunk-major: frag = ks*8 + oi
    int oi = frag & 7;
    int o  = oi * 16 + l15;
    int h  = ks * 32 + (j < 4 ? lg * 4 + j : 16 + lg * 4 + (j - 4));
    ws_s[idx] = f2bs(exp_w2[(e * 128 + o) * 256 + h]);
  } else if (idx < 526336) {
    int i3 = idx - 524288;
    int k = i3 >> 9, lane = (i3 >> 3) & 63, j = i3 & 7;
    int lg = lane >> 4, l15 = lane & 15;
    ws_s[idx] = f2bs(sg_w1[l15 * 128 + k * 32 + lg * 8 + j]);
  } else if (idx < 528384) {
    int i4 = idx - 526336;
    int k = i4 >> 9, lane = (i4 >> 3) & 63, j = i4 & 7;
    int lg = lane >> 4, l15 = lane & 15;
    ws_s[idx] = (l15 < 8) ? f2bs(gate_w[l15 * 128 + k * 32 + lg * 8 + j]) : (short)0;
  } else if (idx < 528896) {
    int i5 = idx - 528384;
    int lane = (i5 >> 3) & 63, j = i5 & 7;
    int lg = lane >> 4, l15 = lane & 15;
    int kk = lg * 8 + j;
    if (l15 < 8 && kk < 16) {
      float acc = 0.f;
      for (int d = 0; d < 128; ++d) acc += gate_w[l15 * 128 + d] * sg_w2[d * 16 + kk];
      ws_s[idx] = f2bs(acc);
    } else {
      ws_s[idx] = 0;
    }
  }
}

__global__ __launch_bounds__(256, 2) void moe_kernel(
    const float* __restrict__ x, const int* __restrict__ active,
    const short* __restrict__ ws_s, float* __restrict__ out) {
  // 2-slot ring: slot = [2 halves][16 frags][512 shorts] = 32KB; total 64KB.
  // Gate-U tiles overlay slot 0. psync: per-wave epoch counters.
  __shared__ __align__(16) short ringS[2][16384];
  __shared__ int psync[4];

  const short* W1p  = ws_s;
  const short* W2p  = ws_s + 262144;
  const short* sg1p = ws_s + 524288;
  const short* gwp  = ws_s + 526336;
  const short* gcp  = ws_s + 528384;

  const int tid  = threadIdx.x;
  const int lane = tid & 63;
  const int wid  = tid >> 6;     // 0..3
  const int l15  = lane & 15;
  const int lg   = lane >> 4;    // 0..3
  const int lw   = wid & 1;      // token group
  const int hf   = wid >> 1;     // expert half (pair id)
  const int eb   = hf * 4;       // expert base
  const int tokw = blockIdx.x * 128 + lw * 64;

  if (lane == 0) psync[wid] = 0;

  // stage phase p for MY half into ring[p&1]; the 2 waves of half hf each
  // stage 8 frags (f = lw*8+t). f<8 = W1 frag f, f>=8 = W2 frag f-8.
  auto stage = [&](int p) {
    int cq = (eb + (p >> 3)) * 8 + (p & 7);
    short* db = &ringS[p & 1][hf * 8192];
#pragma unroll
    for (int t = 0; t < 8; ++t) {
      int f = lw * 8 + t;
      const short* s = (f < 8)
          ? (W1p + ((size_t)cq * 8 + f) * 512 + lane * 8)
          : (W2p + ((size_t)cq * 8 + (f - 8)) * 512 + lane * 8);
      __builtin_amdgcn_global_load_lds(
          (const __attribute__((address_space(1))) void*)s,
          (__attribute__((address_space(3))) void*)(&db[f * 512]),
          16, 0, 0);
    }
  };

  short* Ulw = &ringS[0][0] + wid * 2560;  // per-wave [64][40] bf16 U tile
  for (int i = lane; i < 1280; i += 64) ((int*)Ulw)[i] = 0;

  // ---- X fragments: lane holds row=token(l15 + m*16), k=lg*8+j ----
  bf16x8 xf[4][4];
  {
    int trow = tokw + l15;
#pragma unroll
    for (int m = 0; m < 4; ++m) {
      const float* xr = x + (size_t)(trow + m * 16) * 128;
#pragma unroll
      for (int k = 0; k < 4; ++k) {
        int c = k * 32 + lg * 8;
        float4 a = *(const float4*)(xr + c);
        float4 b = *(const float4*)(xr + c + 4);
        bf16x8 v;
        v[0] = f2bs(a.x); v[1] = f2bs(a.y); v[2] = f2bs(a.z); v[3] = f2bs(a.w);
        v[4] = f2bs(b.x); v[5] = f2bs(b.y); v[6] = f2bs(b.z); v[7] = f2bs(b.w);
        xf[m][k] = v;
      }
    }
  }
  __syncthreads();  // zero-init + psync-init visible before U-writes

  // ---- gate (verified R6/R11/R13 m=4 structure) ----
  float wv4[4][4];  // [my 4 experts][m]
  {
    f32x4 wreg[4];
    bf16x8 sgf[4], gwf[4];
#pragma unroll
    for (int k = 0; k < 4; ++k) {
      sgf[k] = *(const bf16x8*)(sg1p + k * 512 + lane * 8);
      gwf[k] = *(const bf16x8*)(gwp  + k * 512 + lane * 8);
    }
#pragma unroll
    for (int m = 0; m < 4; ++m) {
      f32x4 acc = {0.f, 0.f, 0.f, 0.f};
#pragma unroll
      for (int k = 0; k < 4; ++k)
        acc = __builtin_amdgcn_mfma_f32_16x16x32_bf16(xf[m][k], sgf[k], acc, 0, 0, 0);
#pragma unroll
      for (int r = 0; r < 4; ++r)
        Ulw[(m * 16 + lg * 4 + r) * 40 + l15] = f2bs(fmaxf(acc[r], 0.f));
    }
    f32x4 sc[4];
#pragma unroll
    for (int m = 0; m < 4; ++m) {
      f32x4 acc = {0.f, 0.f, 0.f, 0.f};
#pragma unroll
      for (int k = 0; k < 4; ++k)
        acc = __builtin_amdgcn_mfma_f32_16x16x32_bf16(xf[m][k], gwf[k], acc, 0, 0, 0);
      sc[m] = acc;
    }
    __syncthreads();  // U-writes (rows lg*4+r) visible to uf-reads (rows l15)
    bf16x8 gcf = *(const bf16x8*)(gcp + lane * 8);
#pragma unroll
    for (int m = 0; m < 4; ++m) {
      bf16x8 uf = *(const bf16x8*)(Ulw + (m * 16 + l15) * 40 + lg * 8);
      sc[m] = __builtin_amdgcn_mfma_f32_16x16x32_bf16(uf, gcf, sc[m], 0, 0, 0);
    }
    int b = tokw >> 12;
    float am = (l15 < 8 && active[b * 8 + l15] != 0) ? 0.f : -3.0e38f;
#pragma unroll
    for (int m = 0; m < 4; ++m) {
      f32x4 w4;
#pragma unroll
      for (int r = 0; r < 4; ++r) {
        float s = sc[m][r] + am;
        float mx = s;
        mx = fmaxf(mx, __shfl_xor(mx, 1));
        mx = fmaxf(mx, __shfl_xor(mx, 2));
        mx = fmaxf(mx, __shfl_xor(mx, 4));
        float p = __expf(s - mx);
        float su = p;
        su += __shfl_xor(su, 1);
        su += __shfl_xor(su, 2);
        su += __shfl_xor(su, 4);
        w4[r] = p / su;
      }
      wreg[m] = w4;
    }
    // extract my half's gate weights (R11-verified): wv4[e4][m]
#pragma unroll
    for (int e4 = 0; e4 < 4; ++e4) {
      int srcb = ((l15 >> 2) << 4) | (eb + e4);
      int rp = l15 & 3;
#pragma unroll
      for (int m = 0; m < 4; ++m) {
        float q0 = __shfl(wreg[m][0], srcb), q1 = __shfl(wreg[m][1], srcb);
        float q2 = __shfl(wreg[m][2], srcb), q3 = __shfl(wreg[m][3], srcb);
        float lo = (rp & 1) ? q1 : q0, hi = (rp & 1) ? q3 : q2;
        wv4[e4][m] = (rp & 2) ? hi : lo;
      }
    }
  }
  __syncthreads();  // gate's U reads done; ring slot 0 free for staging

  stage(0);  // depth-1 prologue

  // ---- expert loop: 32 phases, pairwise spin-sync (no block barrier) ----
  f32x4 acc2[4][8];
#pragma unroll
  for (int m = 0; m < 4; ++m)
#pragma unroll
    for (int o = 0; o < 8; ++o)
      acc2[m][o] = {0.f, 0.f, 0.f, 0.f};

  volatile int* vps = (volatile int*)psync;

#pragma unroll 1
  for (int p = 0; p < 32; ++p) {
    const int e4 = p >> 3;
    // own stage(p) loads landed:
    asm volatile("s_waitcnt vmcnt(0)" ::: "memory");
    __builtin_amdgcn_sched_barrier(0);
    // publish epoch, then wait for pair partner (wid^1) to publish:
    if (lane == 0) psync[wid] = p + 1;
    while (vps[wid ^ 1] < p + 1) __builtin_amdgcn_s_sleep(1);
    asm volatile("" ::: "memory");
    __builtin_amdgcn_sched_barrier(0);
    if (p + 1 < 32) stage(p + 1);  // WAR-safe: partner passed sync(p)

    const short* rb = &ringS[p & 1][hf * 8192];
    __builtin_amdgcn_s_setprio(1);

    // G1 + immediate pack (Af 4-at-a-time; static hu indexing) — R13/R14 body
    union HU { unsigned u[4]; bf16x8 v; };
    HU hu[4];
#pragma unroll
    for (int n = 0; n < 2; ++n) {
      bf16x8 Af[4];
#pragma unroll
      for (int kx = 0; kx < 4; ++kx)
        Af[kx] = *(const bf16x8*)(rb + (n * 4 + kx) * 512 + lane * 8);
#pragma unroll
      for (int m = 0; m < 4; ++m) {
        f32x4 a = {0.f, 0.f, 0.f, 0.f};
#pragma unroll
        for (int kx = 0; kx < 4; ++kx)
          a = __builtin_amdgcn_mfma_f32_16x16x32_bf16(Af[kx], xf[m][kx], a, 0, 0, 0);
        float s = wv4[e4][m];
        hu[m].u[n * 2]     = pk2(fmaxf(a[0], 0.f) * s, fmaxf(a[1], 0.f) * s);
        hu[m].u[n * 2 + 1] = pk2(fmaxf(a[2], 0.f) * s, fmaxf(a[3], 0.f) * s);
      }
    }
    // G2: acc2[m][o] += mfma(W2frag[o], hB[m])  (D[out][token])
#pragma unroll
    for (int o = 0; o < 8; ++o) {
      bf16x8 Bf = *(const bf16x8*)(rb + 4096 + o * 512 + lane * 8);
#pragma unroll
      for (int m = 0; m < 4; ++m)
        acc2[m][o] = __builtin_amdgcn_mfma_f32_16x16x32_bf16(Bf, hu[m].v, acc2[m][o], 0, 0, 0);
    }
    __builtin_amdgcn_s_setprio(0);
  }

  // ---- epilogue: combine halves via LDS (R10/R14-verified 2-round) ----
  __syncthreads();
  float* ep = (float*)&ringS[0][0];  // regions (lw*2+mm)*2112 floats, [16][132]
#pragma unroll
  for (int rr = 0; rr < 2; ++rr) {
    if (hf == 1) {
#pragma unroll
      for (int mm = 0; mm < 2; ++mm) {
#pragma unroll
        for (int o = 0; o < 8; ++o)
          *(f32x4*)&ep[(lw * 2 + mm) * 2112 + l15 * 132 + o * 16 + lg * 4] =
              acc2[rr * 2 + mm][o];
      }
    }
    __syncthreads();
    if (hf == 0) {
#pragma unroll
      for (int mm = 0; mm < 2; ++mm) {
#pragma unroll
        for (int o = 0; o < 8; ++o) {
          f32x4 v = *(const f32x4*)&ep[(lw * 2 + mm) * 2112 + l15 * 132 + o * 16 + lg * 4];
          f32x4 r = acc2[rr * 2 + mm][o];
          r[0] += v[0]; r[1] += v[1]; r[2] += v[2]; r[3] += v[3];
          *(f32x4*)(out + (size_t)(tokw + (rr * 2 + mm) * 16 + l15) * 128 + o * 16 + lg * 4) = r;
        }
      }
    }
    __syncthreads();
  }
  if (blockIdx.x == 0 && tid == 0) out[8388608] = 0.0f;  // aux_loss
}

extern "C" void kernel_launch(void* const* d_in, const int* in_sizes, int n_in,
                              void* d_out, int out_size, void* d_ws, size_t ws_size,
                              hipStream_t stream) {
  const float* x      = (const float*)d_in[0];
  const int*   act    = (const int*)d_in[1];
  const float* sg_w1  = (const float*)d_in[2];
  const float* sg_w2  = (const float*)d_in[3];
  const float* gate_w = (const float*)d_in[4];
  const float* exp_w1 = (const float*)d_in[5];
  const float* exp_w2 = (const float*)d_in[6];
  short* ws_s = (short*)d_ws;
  float* out = (float*)d_out;

  prep_kernel<<<2066, 256, 0, stream>>>(sg_w1, sg_w2, gate_w, exp_w1, exp_w2, ws_s);
  moe_kernel<<<512, 256, 0, stream>>>(x, act, ws_s, out);
}